// Round 7
// baseline (111.051 us; speedup 1.0000x reference)
//
#include <hip/hip_runtime.h>
#include <hip/hip_bf16.h>
#include <stdint.h>

#define NPIX 512
#define NBC  96
#define NWG8 (NBC * 4)      // 384 blocks: 96 images x 2x2 tiles of 256^2

typedef __attribute__((ext_vector_type(8))) short bf16x8;
typedef __attribute__((ext_vector_type(4))) float f32x4;
typedef __attribute__((ext_vector_type(8))) unsigned short u16x8;

__device__ __forceinline__ unsigned short f2bf(float f) {
    __hip_bfloat16 h = __float2bfloat16(f);
    union { __hip_bfloat16 h; unsigned short u; } v;
    v.h = h;
    return v.u;
}

#define GLD16(g, l) __builtin_amdgcn_global_load_lds( \
    (const __attribute__((address_space(1))) void*)(const void*)(g), \
    (__attribute__((address_space(3))) void*)(void*)(l), 16, 0, 0)

#define SBAR() do { __builtin_amdgcn_sched_barrier(0); \
                    __builtin_amdgcn_s_barrier(); \
                    __builtin_amdgcn_sched_barrier(0); } while (0)
#define LGKM0() do { asm volatile("s_waitcnt lgkmcnt(0)" ::: "memory"); \
                     __builtin_amdgcn_sched_barrier(0); } while (0)

// ---------------- D basis: D[k][n] = bf16(2*cos(pi*(2n+1)*k/1024)) ----------------
__global__ void k_basis(unsigned short* __restrict__ D) {
    int idx = blockIdx.x * 256 + threadIdx.x;
    int k = idx >> 9, n = idx & 511;
    int m = ((2 * n + 1) * k) & 2047;
    float ang = (float)m * 3.06796157577128218e-03f;  // pi/1024
    D[idx] = f2bf(2.0f * cosf(ang));
}

// ---------------- cvt: X fp32 -> bf16, 16 elems/thread ----------------
__global__ __launch_bounds__(256) void k_cvt(const float* __restrict__ X,
                                             unsigned short* __restrict__ Xbf) {
    size_t t = (size_t)blockIdx.x * 256 + threadIdx.x;
    const float4* src = (const float4*)X + t * 4;
    float4 a = src[0], b = src[1], c = src[2], d = src[3];
    u16x8 w0, w1;
    w0[0] = f2bf(a.x); w0[1] = f2bf(a.y); w0[2] = f2bf(a.z); w0[3] = f2bf(a.w);
    w0[4] = f2bf(b.x); w0[5] = f2bf(b.y); w0[6] = f2bf(b.z); w0[7] = f2bf(b.w);
    w1[0] = f2bf(c.x); w1[1] = f2bf(c.y); w1[2] = f2bf(c.z); w1[3] = f2bf(c.w);
    w1[4] = f2bf(d.x); w1[5] = f2bf(d.y); w1[6] = f2bf(d.z); w1[7] = f2bf(d.w);
    u16x8* dst = (u16x8*)Xbf + t * 2;
    dst[0] = w0;
    dst[1] = w1;
}

// ------------- Stage 1: sT[l][h] = bf16( (Xbf @ D^T)[h][l] ) -------------
// 8-phase 256^2 BT-GEMM, both operands bf16 via global_load_lds; counted vmcnt.
// Standalone (non-template) kernel: transposed bf16 epilogue via 128KB LDS overlay.
__global__ __launch_bounds__(512) void k_s1g(
        const unsigned short* __restrict__ Xbf,
        const unsigned short* __restrict__ D,
        unsigned short* __restrict__ sT) {
    __shared__ __align__(16) char LDS[131072];

    const int bid = blockIdx.x;
    const int nb  = (bid & 7) * (NWG8 / 8) + (bid >> 3);
    const int bc = nb >> 2, mt = (nb >> 1) & 1, nt = nb & 1;
    const int mA0 = mt * 256, nB0 = nt * 256;
    const unsigned short* Aimg = Xbf + (size_t)bc * NPIX * NPIX;
    const unsigned short* Bimg = D;                    // shared basis, stride 0

    const int tid  = threadIdx.x;
    const int lane = tid & 63;
    const int wid  = tid >> 6;
    const int wr = wid >> 2, wc = wid & 3;
    const int rm = lane & 15;
    const int kq = lane >> 4;

    f32x4 acc[8][4] = {};
    bf16x8 a[4][2], b0[2][2], b1[2][2];

    auto stageA = [&](int kt, int p, int H) {
        char* dst = LDS + p * 32768 + H * 16384;
        #pragma unroll
        for (int it = 0; it < 2; ++it) {
            int c = it * 512 + tid;
            int rp = c >> 3, g = c & 7;
            int gs = g ^ (rp & 7);
            int row = ((rp >> 6) << 7) + H * 64 + (rp & 63);
            GLD16(Aimg + (size_t)(mA0 + row) * NPIX + kt * 64 + gs * 8, dst + c * 16);
        }
    };
    auto stageB = [&](int kt, int p, int H) {
        char* dst = LDS + 65536 + p * 32768 + H * 16384;
        #pragma unroll
        for (int it = 0; it < 2; ++it) {
            int c = it * 512 + tid;
            int rp = c >> 3, g = c & 7;
            int gs = g ^ (rp & 7);
            int row = ((rp >> 5) << 6) + H * 32 + (rp & 31);
            GLD16(Bimg + (size_t)(nB0 + row) * NPIX + kt * 64 + gs * 8, dst + c * 16);
        }
    };
    auto readA = [&](int p, int mh) {
        const char* base = LDS + p * 32768 + mh * 16384;
        #pragma unroll
        for (int f = 0; f < 4; ++f) {
            int rp = wr * 64 + f * 16 + rm;
            #pragma unroll
            for (int ks = 0; ks < 2; ++ks) {
                int slot = (ks * 4 + kq) ^ (rm & 7);
                a[f][ks] = *(const bf16x8*)(base + rp * 128 + slot * 16);
            }
        }
    };
    auto readB = [&](int p, int nh, bf16x8 (&b)[2][2]) {
        const char* base = LDS + 65536 + p * 32768 + nh * 16384;
        #pragma unroll
        for (int jj = 0; jj < 2; ++jj) {
            int rp = wc * 32 + jj * 16 + rm;
            #pragma unroll
            for (int ks = 0; ks < 2; ++ks) {
                int slot = (ks * 4 + kq) ^ (rm & 7);
                b[jj][ks] = *(const bf16x8*)(base + rp * 128 + slot * 16);
            }
        }
    };
    auto mma = [&](int mh, int nh, bf16x8 (&b)[2][2]) {
        __builtin_amdgcn_s_setprio(1);
        #pragma unroll
        for (int f = 0; f < 4; ++f)
            #pragma unroll
            for (int jj = 0; jj < 2; ++jj)
                #pragma unroll
                for (int ks = 0; ks < 2; ++ks)
                    acc[mh * 4 + f][nh * 2 + jj] = __builtin_amdgcn_mfma_f32_16x16x32_bf16(
                        a[f][ks], b[jj][ks], acc[mh * 4 + f][nh * 2 + jj], 0, 0, 0);
        __builtin_amdgcn_s_setprio(0);
    };

    stageA(0, 0, 0); stageB(0, 0, 0); stageB(0, 0, 1); stageA(0, 0, 1);

    for (int T = 0; T < 7; ++T) {
        const int p = T & 1, pn = p ^ 1;
        asm volatile("s_waitcnt vmcnt(4)" ::: "memory"); SBAR();
        readA(p, 0); readB(p, 0, b0); stageA(T + 1, pn, 0);
        LGKM0(); mma(0, 0, b0);
        asm volatile("s_waitcnt vmcnt(4)" ::: "memory"); SBAR();
        readB(p, 1, b1); stageB(T + 1, pn, 0);
        LGKM0(); mma(0, 1, b1);
        asm volatile("s_waitcnt vmcnt(4)" ::: "memory"); SBAR();
        readA(p, 1); stageB(T + 1, pn, 1);
        LGKM0(); mma(1, 0, b0);
        SBAR();
        stageA(T + 1, pn, 1);
        mma(1, 1, b1);
    }
    {
        asm volatile("s_waitcnt vmcnt(4)" ::: "memory"); SBAR();
        readA(1, 0); readB(1, 0, b0); LGKM0(); mma(0, 0, b0);
        asm volatile("s_waitcnt vmcnt(2)" ::: "memory"); SBAR();
        readB(1, 1, b1); LGKM0(); mma(0, 1, b1);
        asm volatile("s_waitcnt vmcnt(0)" ::: "memory"); SBAR();
        readA(1, 1); LGKM0(); mma(1, 0, b0);
        SBAR();
        mma(1, 1, b1);
    }

    // Transposed bf16 epilogue through the (now dead) 128KB staging LDS.
    SBAR();
    #pragma unroll
    for (int mh = 0; mh < 2; ++mh)
        #pragma unroll
        for (int f = 0; f < 4; ++f) {
            int h_loc = wr * 128 + mh * 64 + f * 16 + kq * 4;
            #pragma unroll
            for (int nh = 0; nh < 2; ++nh)
                #pragma unroll
                for (int jj = 0; jj < 2; ++jj) {
                    int l_loc = wc * 64 + (nh * 2 + jj) * 16 + rm;
                    int byte = (l_loc * 512 + h_loc * 2) ^ ((l_loc & 7) << 4);
                    f32x4 v = acc[mh * 4 + f][nh * 2 + jj];
                    ushort4 w;
                    w.x = f2bf(v[0]); w.y = f2bf(v[1]);
                    w.z = f2bf(v[2]); w.w = f2bf(v[3]);
                    *(ushort4*)(LDS + byte) = w;
                }
        }
    LGKM0(); SBAR();
    unsigned short* Co = sT + (size_t)bc * NPIX * NPIX;
    #pragma unroll
    for (int i = 0; i < 16; ++i) {
        int chunk = i * 512 + tid;
        int l_loc = chunk >> 5, g = chunk & 31;
        int byte = (l_loc * 512 + g * 16) ^ ((l_loc & 7) << 4);
        u16x8 v = *(const u16x8*)(LDS + byte);
        *(u16x8*)&Co[(size_t)(nB0 + l_loc) * NPIX + mA0 + g * 8] = v;
    }
}

// ------------- Stage 2: out[k][l] = (D @ sT^T)[k][l] * 1e-3 (byte-identical to R6) -------------
__global__ __launch_bounds__(512) void k_s2g(
        const unsigned short* __restrict__ D,
        const unsigned short* __restrict__ sT,
        float* __restrict__ Cv) {
    __shared__ __align__(16) char LDS[131072];

    const int bid = blockIdx.x;
    const int nb  = (bid & 7) * (NWG8 / 8) + (bid >> 3);
    const int bc = nb >> 2, mt = (nb >> 1) & 1, nt = nb & 1;
    const int mA0 = mt * 256, nB0 = nt * 256;
    const unsigned short* Aimg = D;                    // shared basis, stride 0
    const unsigned short* Bimg = sT + (size_t)bc * NPIX * NPIX;

    const int tid  = threadIdx.x;
    const int lane = tid & 63;
    const int wid  = tid >> 6;
    const int wr = wid >> 2, wc = wid & 3;
    const int rm = lane & 15;
    const int kq = lane >> 4;

    f32x4 acc[8][4] = {};
    bf16x8 a[4][2], b0[2][2], b1[2][2];

    auto stageA = [&](int kt, int p, int H) {
        char* dst = LDS + p * 32768 + H * 16384;
        #pragma unroll
        for (int it = 0; it < 2; ++it) {
            int c = it * 512 + tid;
            int rp = c >> 3, g = c & 7;
            int gs = g ^ (rp & 7);
            int row = ((rp >> 6) << 7) + H * 64 + (rp & 63);
            GLD16(Aimg + (size_t)(mA0 + row) * NPIX + kt * 64 + gs * 8, dst + c * 16);
        }
    };
    auto stageB = [&](int kt, int p, int H) {
        char* dst = LDS + 65536 + p * 32768 + H * 16384;
        #pragma unroll
        for (int it = 0; it < 2; ++it) {
            int c = it * 512 + tid;
            int rp = c >> 3, g = c & 7;
            int gs = g ^ (rp & 7);
            int row = ((rp >> 5) << 6) + H * 32 + (rp & 31);
            GLD16(Bimg + (size_t)(nB0 + row) * NPIX + kt * 64 + gs * 8, dst + c * 16);
        }
    };
    auto readA = [&](int p, int mh) {
        const char* base = LDS + p * 32768 + mh * 16384;
        #pragma unroll
        for (int f = 0; f < 4; ++f) {
            int rp = wr * 64 + f * 16 + rm;
            #pragma unroll
            for (int ks = 0; ks < 2; ++ks) {
                int slot = (ks * 4 + kq) ^ (rm & 7);
                a[f][ks] = *(const bf16x8*)(base + rp * 128 + slot * 16);
            }
        }
    };
    auto readB = [&](int p, int nh, bf16x8 (&b)[2][2]) {
        const char* base = LDS + 65536 + p * 32768 + nh * 16384;
        #pragma unroll
        for (int jj = 0; jj < 2; ++jj) {
            int rp = wc * 32 + jj * 16 + rm;
            #pragma unroll
            for (int ks = 0; ks < 2; ++ks) {
                int slot = (ks * 4 + kq) ^ (rm & 7);
                b[jj][ks] = *(const bf16x8*)(base + rp * 128 + slot * 16);
            }
        }
    };
    auto mma = [&](int mh, int nh, bf16x8 (&b)[2][2]) {
        __builtin_amdgcn_s_setprio(1);
        #pragma unroll
        for (int f = 0; f < 4; ++f)
            #pragma unroll
            for (int jj = 0; jj < 2; ++jj)
                #pragma unroll
                for (int ks = 0; ks < 2; ++ks)
                    acc[mh * 4 + f][nh * 2 + jj] = __builtin_amdgcn_mfma_f32_16x16x32_bf16(
                        a[f][ks], b[jj][ks], acc[mh * 4 + f][nh * 2 + jj], 0, 0, 0);
        __builtin_amdgcn_s_setprio(0);
    };

    stageA(0, 0, 0); stageB(0, 0, 0); stageB(0, 0, 1); stageA(0, 0, 1);

    for (int T = 0; T < 7; ++T) {
        const int p = T & 1, pn = p ^ 1;
        asm volatile("s_waitcnt vmcnt(4)" ::: "memory"); SBAR();
        readA(p, 0); readB(p, 0, b0); stageA(T + 1, pn, 0);
        LGKM0(); mma(0, 0, b0);
        asm volatile("s_waitcnt vmcnt(4)" ::: "memory"); SBAR();
        readB(p, 1, b1); stageB(T + 1, pn, 0);
        LGKM0(); mma(0, 1, b1);
        asm volatile("s_waitcnt vmcnt(4)" ::: "memory"); SBAR();
        readA(p, 1); stageB(T + 1, pn, 1);
        LGKM0(); mma(1, 0, b0);
        SBAR();
        stageA(T + 1, pn, 1);
        mma(1, 1, b1);
    }
    {
        asm volatile("s_waitcnt vmcnt(4)" ::: "memory"); SBAR();
        readA(1, 0); readB(1, 0, b0); LGKM0(); mma(0, 0, b0);
        asm volatile("s_waitcnt vmcnt(2)" ::: "memory"); SBAR();
        readB(1, 1, b1); LGKM0(); mma(0, 1, b1);
        asm volatile("s_waitcnt vmcnt(0)" ::: "memory"); SBAR();
        readA(1, 1); LGKM0(); mma(1, 0, b0);
        SBAR();
        mma(1, 1, b1);
    }

    float* Co = Cv + (size_t)bc * NPIX * NPIX;
    #pragma unroll
    for (int mh = 0; mh < 2; ++mh)
        #pragma unroll
        for (int f = 0; f < 4; ++f) {
            int k_ = mA0 + wr * 128 + mh * 64 + f * 16 + kq * 4;
            #pragma unroll
            for (int nh = 0; nh < 2; ++nh)
                #pragma unroll
                for (int jj = 0; jj < 2; ++jj) {
                    int l_ = nB0 + wc * 64 + (nh * 2 + jj) * 16 + rm;
                    f32x4 v = acc[mh * 4 + f][nh * 2 + jj];
                    #pragma unroll
                    for (int r = 0; r < 4; ++r)
                        Co[(size_t)(k_ + r) * NPIX + l_] = v[r] * 1.0e-3f;
                }
        }
}

extern "C" void kernel_launch(void* const* d_in, const int* in_sizes, int n_in,
                              void* d_out, int out_size, void* d_ws, size_t ws_size,
                              hipStream_t stream) {
    const float* img = (const float*)d_in[0];
    float* out = (float*)d_out;

    const size_t ST_OFF = 512 * 1024;                     // 512 KB for D
    const size_t ST_SZ  = (size_t)NBC * NPIX * NPIX * 2;  // 48 MB
    const size_t XBF_SZ = ST_SZ;

    unsigned short* D  = (unsigned short*)d_ws;
    unsigned short* sT = (unsigned short*)((char*)d_ws + ST_OFF);
    unsigned short* Xbf;
    if (ws_size >= ST_OFF + ST_SZ + XBF_SZ)
        Xbf = (unsigned short*)((char*)d_ws + ST_OFF + ST_SZ);
    else
        Xbf = (unsigned short*)d_out;                     // dead until stage2 overwrites

    k_basis<<<dim3(512 * 512 / 256), dim3(256), 0, stream>>>(D);
    k_cvt<<<dim3((int)((size_t)NBC * NPIX * NPIX / 16 / 256)), dim3(256), 0, stream>>>(img, Xbf);

    // Stage 1: sT[l][h] = bf16( (Xbf @ D^T)[h][l] )
    k_s1g<<<dim3(NWG8), dim3(512), 0, stream>>>(Xbf, D, sT);
    // Stage 2: out[k][l] = (D @ sT^T)[k][l] * 1e-3
    k_s2g<<<dim3(NWG8), dim3(512), 0, stream>>>(D, sT, out);
}